// Round 4
// baseline (391.576 us; speedup 1.0000x reference)
//
#include <hip/hip_runtime.h>
#include <hip/hip_cooperative_groups.h>
#include <math.h>

namespace cg = cooperative_groups;

#define L_SEQ 8192
#define B_N   8

// Workspace layout (float offsets) — total ~1.3 MB
#define QRAW_OFF   0                        // [1683] (fallback path only)
#define QF_OFF     2048                     // [512]  (fallback path only)
#define QKV_OFF    2560                     // [8][512] = 4096 (pre-scaled by 0.125)
#define CK_OFF     6656                     // [8] (pre-scaled by 0.125)
#define YREP_OFF   8192                     // [8 rep][8 b][8 h][512 c] = 262144
#define DREP_OFF   (YREP_OFF + 262144)      // [8 rep][8 b][8 h] = 512 (contiguous after YREP)
#define V_OFF      (DREP_OFF + 512)         // [8][512] = 4096
#define ROW_OFF    (V_OFF + 4096)           // [8][512] = 4096
#define QFP_OFF    (ROW_OFF + 4096)         // [106][512] = 54272 qf partials (mega path)

// ============================ MEGA (cooperative) ============================
__global__ __launch_bounds__(256, 2) void mega(
    const float* __restrict__ x,   const float* __restrict__ poi,
    const float* __restrict__ wq1, const float* __restrict__ bq1,
    const float* __restrict__ wq2, const float* __restrict__ bq2,
    const float* __restrict__ wk,  const float* __restrict__ bk,
    const float* __restrict__ wv,  const float* __restrict__ bv,
    const float* __restrict__ wo,  const float* __restrict__ bo,
    float* __restrict__ ws, float* __restrict__ out)
{
    cg::grid_group grid = cg::this_grid();
    __shared__ float smem[4104];
    const int t = threadIdx.x;
    const int bid = blockIdx.x;

    // ---- P0: zero YREP/DREP, init V=bv row=bo; qraw + qf partials (blocks 0..105) ----
    {
        int gid = bid * 256 + t;
        for (int i = gid; i < 262656; i += 131072) ws[YREP_OFF + i] = 0.f;
        if (gid < 4096) {
            ws[V_OFF + gid]   = bv[gid & 511];
            ws[ROW_OFF + gid] = bo[gid & 511];
        }
        if (bid < 106) {
            int i0 = bid * 16;
            int cnt = 1683 - i0; if (cnt > 16) cnt = 16;
            if (t < cnt) {
                float a = bq1[0];
#pragma unroll
                for (int j = 0; j < 24; ++j) a += poi[(i0 + t) * 24 + j] * wq1[j];
                smem[t] = a;
            }
            __syncthreads();
            float a0 = 0.f, a1 = 0.f;
            for (int ii = 0; ii < cnt; ++ii) {
                float q = smem[ii];
                const float* w2 = wq2 + (size_t)(i0 + ii) * 512;
                a0 += q * w2[t];
                a1 += q * w2[t + 256];
            }
            ws[QFP_OFF + bid * 512 + t]       = a0;
            ws[QFP_OFF + bid * 512 + 256 + t] = a1;
        }
    }
    grid.sync();

    // ---- P0c: qf = bq2 + sum partials; qkvec + ck (blocks 0..15) ----
    if (bid < 16) {
        for (int o = t; o < 512; o += 256) {
            float s = bq2[o];
            for (int k = 0; k < 106; ++k) s += ws[QFP_OFF + k * 512 + o];
            smem[o] = s;
        }
        __syncthreads();
        int idx = bid * 256 + t, h = idx >> 9, c = idx & 511;
        float a = 0.f;
#pragma unroll 8
        for (int e = 0; e < 64; ++e) a += smem[h * 64 + e] * wk[(size_t)c * 512 + h * 64 + e];
        ws[QKV_OFF + idx] = 0.125f * a;
        if (idx < 8) {
            float bsum = 0.f;
            for (int e = 0; e < 64; ++e) bsum += smem[idx * 64 + e] * bk[idx * 64 + e];
            ws[CK_OFF + idx] = 0.125f * bsum;
        }
    }
    grid.sync();

    // ---- P1: fused single pass (scores -> exp -> weighted sum) ----
    {
        int lane = t & 63, w = t >> 6;
        int b = bid >> 6, slot = bid & 63;
        int wslot = slot * 4 + w;

        float4 qa[8], qb[8];
        const float4* qk4 = (const float4*)(ws + QKV_OFF);
#pragma unroll
        for (int h = 0; h < 8; ++h) {
            qa[h] = qk4[h * 128 + lane * 2];
            qb[h] = qk4[h * 128 + lane * 2 + 1];
        }
        float ck[8];
#pragma unroll
        for (int h = 0; h < 8; ++h) ck[h] = ws[CK_OFF + h];

        float num[8][8] = {{0.f}};
        float den[8] = {0.f};

        const float4* xp = (const float4*)(x + (size_t)b * L_SEQ * 512);
        float4 cxa = xp[(size_t)wslot * 128 + lane * 2];
        float4 cxb = xp[(size_t)wslot * 128 + lane * 2 + 1];

        for (int r = wslot; r < L_SEQ; r += 256) {
            int rn = r + 256;
            float4 nxa = cxa, nxb = cxb;
            if (rn < L_SEQ) {
                nxa = xp[(size_t)rn * 128 + lane * 2];
                nxb = xp[(size_t)rn * 128 + lane * 2 + 1];
            }
            float p[8];
#pragma unroll
            for (int h = 0; h < 8; ++h)
                p[h] = cxa.x * qa[h].x + cxa.y * qa[h].y + cxa.z * qa[h].z + cxa.w * qa[h].w
                     + cxb.x * qb[h].x + cxb.y * qb[h].y + cxb.z * qb[h].z + cxb.w * qb[h].w;
#pragma unroll
            for (int m = 32; m >= 1; m >>= 1) {
#pragma unroll
                for (int h = 0; h < 8; ++h) p[h] += __shfl_xor(p[h], m, 64);
            }
#pragma unroll
            for (int h = 0; h < 8; ++h) {
                float wg = __expf(p[h] + ck[h]);
                den[h] += wg;
                num[h][0] += wg * cxa.x; num[h][1] += wg * cxa.y;
                num[h][2] += wg * cxa.z; num[h][3] += wg * cxa.w;
                num[h][4] += wg * cxb.x; num[h][5] += wg * cxb.y;
                num[h][6] += wg * cxb.z; num[h][7] += wg * cxb.w;
            }
            cxa = nxa; cxb = nxb;
        }

        for (int wi = 0; wi < 4; ++wi) {
            if (w == wi) {
#pragma unroll
                for (int h = 0; h < 8; ++h) {
                    int base = h * 512 + lane * 8;
                    if (wi == 0) {
#pragma unroll
                        for (int j = 0; j < 8; ++j) smem[base + j] = num[h][j];
                        if (lane == 0) smem[4096 + h] = den[h];
                    } else {
#pragma unroll
                        for (int j = 0; j < 8; ++j) smem[base + j] += num[h][j];
                        if (lane == 0) smem[4096 + h] += den[h];
                    }
                }
            }
            __syncthreads();
        }
        int rep = bid & 7;
        float* yrep = ws + YREP_OFF + ((size_t)rep * 8 + b) * 4096;
#pragma unroll
        for (int k = 0; k < 16; ++k) atomicAdd(yrep + k * 256 + t, smem[k * 256 + t]);
        if (t < 8) atomicAdd(ws + DREP_OFF + (rep * 8 + b) * 8 + t, smem[4096 + t]);
    }
    grid.sync();

    // ---- P2: V[b,o] += sum_{c chunk} yn*wv (blocks 0..127) ----
    if (bid < 128) {
        int b = bid >> 4, c0 = (bid & 15) * 32;
        if (t < 8) {
            float s = 0.f;
#pragma unroll
            for (int rep = 0; rep < 8; ++rep) s += ws[DREP_OFF + (rep * 8 + b) * 8 + t];
            smem[256 + t] = 1.f / s;
        }
        __syncthreads();
        {
            int h = t >> 5, cl = t & 31;
            float s = 0.f;
#pragma unroll
            for (int rep = 0; rep < 8; ++rep)
                s += ws[YREP_OFF + ((size_t)rep * 8 + b) * 4096 + h * 512 + c0 + cl];
            smem[t] = s * smem[256 + h];
        }
        __syncthreads();
        float acc0 = 0.f, acc1 = 0.f;
        int h0 = t >> 6, h1 = (t + 256) >> 6;
#pragma unroll 8
        for (int ci = 0; ci < 32; ++ci) {
            const float* wr = wv + (size_t)(c0 + ci) * 512;
            acc0 += smem[h0 * 32 + ci] * wr[t];
            acc1 += smem[h1 * 32 + ci] * wr[t + 256];
        }
        atomicAdd(ws + V_OFF + b * 512 + t,       acc0);
        atomicAdd(ws + V_OFF + b * 512 + t + 256, acc1);
    }
    grid.sync();

    // ---- P3: row[b,j] += sum_{o chunk} V*wo (blocks 0..127) ----
    if (bid < 128) {
        int b = bid >> 4, o0 = (bid & 15) * 32;
        if (t < 32) smem[t] = ws[V_OFF + b * 512 + o0 + t];
        __syncthreads();
        float acc0 = 0.f, acc1 = 0.f;
#pragma unroll 8
        for (int oi = 0; oi < 32; ++oi) {
            const float* wr = wo + (size_t)(o0 + oi) * 512;
            float v = smem[oi];
            acc0 += v * wr[t];
            acc1 += v * wr[t + 256];
        }
        atomicAdd(ws + ROW_OFF + b * 512 + t,       acc0);
        atomicAdd(ws + ROW_OFF + b * 512 + t + 256, acc1);
    }
    grid.sync();

    // ---- P4: broadcast out[b,l,:] = row[b,:] ----
    {
        const float4* row4 = (const float4*)(ws + ROW_OFF);
        float4* out4 = (float4*)out;
        for (size_t g = (size_t)bid * 256 + t; g < 8388608ull; g += 131072) {
            int b = (int)(g >> 20), q = (int)(g & 127);
            out4[g] = row4[b * 128 + q];
        }
    }
}

// ===================== FALLBACK (round-3 proven path) =====================
__global__ void k0_init(float* ws, const float* __restrict__ bv, const float* __restrict__ bo,
                        const float* __restrict__ bq2) {
    int i = blockIdx.x * 256 + threadIdx.x;
    if (i < 262656)      ws[YREP_OFF + i] = 0.f;
    else if (i < 266752) ws[V_OFF + (i - 262656)] = bv[(i - 262656) & 511];
    else if (i < 270848) ws[ROW_OFF + (i - 266752)] = bo[(i - 266752) & 511];
    else if (i < 271360) ws[QF_OFF + (i - 270848)] = bq2[i - 270848];
}

__global__ void k1_qraw(const float* __restrict__ poi, const float* __restrict__ wq1,
                        const float* __restrict__ bq1, float* ws) {
    int i = blockIdx.x * 256 + threadIdx.x;
    if (i >= 1683) return;
    float a = bq1[0];
#pragma unroll
    for (int j = 0; j < 24; ++j) a += poi[i * 24 + j] * wq1[j];
    ws[QRAW_OFF + i] = a;
}

__global__ __launch_bounds__(512) void k2_qf(const float* __restrict__ wq2, float* ws) {
    __shared__ float qr[32];
    int k = blockIdx.x, t = threadIdx.x;
    int i0 = k * 32;
    int cnt = 1683 - i0; if (cnt > 32) cnt = 32;
    if (t < cnt) qr[t] = ws[QRAW_OFF + i0 + t];
    __syncthreads();
    float a = 0.f;
    for (int ii = 0; ii < cnt; ++ii) a += qr[ii] * wq2[(size_t)(i0 + ii) * 512 + t];
    atomicAdd(ws + QF_OFF + t, a);
}

__global__ void k3_qkvec(const float* __restrict__ wk, const float* __restrict__ bk, float* ws) {
    __shared__ float qf[512];
    int t = threadIdx.x;
    for (int t2 = t; t2 < 512; t2 += 256) qf[t2] = ws[QF_OFF + t2];
    __syncthreads();
    int idx = blockIdx.x * 256 + t;
    int h = idx >> 9, c = idx & 511;
    float a = 0.f;
#pragma unroll 8
    for (int e = 0; e < 64; ++e) a += qf[h * 64 + e] * wk[(size_t)c * 512 + h * 64 + e];
    ws[QKV_OFF + idx] = 0.125f * a;
    if (idx < 8) {
        float bsum = 0.f;
        for (int e = 0; e < 64; ++e) bsum += qf[idx * 64 + e] * bk[idx * 64 + e];
        ws[CK_OFF + idx] = 0.125f * bsum;
    }
}

__global__ __launch_bounds__(256, 2) void kF(const float* __restrict__ x, float* ws) {
    int t = threadIdx.x;
    int lane = t & 63, w = t >> 6;
    int b = blockIdx.x >> 6, slot = blockIdx.x & 63;
    int wslot = slot * 4 + w;

    float4 qa[8], qb[8];
    const float4* qk4 = (const float4*)(ws + QKV_OFF);
#pragma unroll
    for (int h = 0; h < 8; ++h) {
        qa[h] = qk4[h * 128 + lane * 2];
        qb[h] = qk4[h * 128 + lane * 2 + 1];
    }
    float ck[8];
#pragma unroll
    for (int h = 0; h < 8; ++h) ck[h] = ws[CK_OFF + h];

    float num[8][8] = {{0.f}};
    float den[8] = {0.f};

    const float4* xp = (const float4*)(x + (size_t)b * L_SEQ * 512);
    float4 cxa = xp[(size_t)wslot * 128 + lane * 2];
    float4 cxb = xp[(size_t)wslot * 128 + lane * 2 + 1];

    for (int r = wslot; r < L_SEQ; r += 256) {
        int rn = r + 256;
        float4 nxa = cxa, nxb = cxb;
        if (rn < L_SEQ) {
            nxa = xp[(size_t)rn * 128 + lane * 2];
            nxb = xp[(size_t)rn * 128 + lane * 2 + 1];
        }
        float p[8];
#pragma unroll
        for (int h = 0; h < 8; ++h)
            p[h] = cxa.x * qa[h].x + cxa.y * qa[h].y + cxa.z * qa[h].z + cxa.w * qa[h].w
                 + cxb.x * qb[h].x + cxb.y * qb[h].y + cxb.z * qb[h].z + cxb.w * qb[h].w;
#pragma unroll
        for (int m = 32; m >= 1; m >>= 1) {
#pragma unroll
            for (int h = 0; h < 8; ++h) p[h] += __shfl_xor(p[h], m, 64);
        }
#pragma unroll
        for (int h = 0; h < 8; ++h) {
            float wg = __expf(p[h] + ck[h]);
            den[h] += wg;
            num[h][0] += wg * cxa.x; num[h][1] += wg * cxa.y;
            num[h][2] += wg * cxa.z; num[h][3] += wg * cxa.w;
            num[h][4] += wg * cxb.x; num[h][5] += wg * cxb.y;
            num[h][6] += wg * cxb.z; num[h][7] += wg * cxb.w;
        }
        cxa = nxa; cxb = nxb;
    }

    __shared__ float num_s[4096];
    __shared__ float den_s[8];
    for (int wi = 0; wi < 4; ++wi) {
        if (w == wi) {
#pragma unroll
            for (int h = 0; h < 8; ++h) {
                int base = h * 512 + lane * 8;
                if (wi == 0) {
#pragma unroll
                    for (int j = 0; j < 8; ++j) num_s[base + j] = num[h][j];
                    if (lane == 0) den_s[h] = den[h];
                } else {
#pragma unroll
                    for (int j = 0; j < 8; ++j) num_s[base + j] += num[h][j];
                    if (lane == 0) den_s[h] += den[h];
                }
            }
        }
        __syncthreads();
    }
    int rep = blockIdx.x & 7;
    float* yrep = ws + YREP_OFF + ((size_t)rep * 8 + b) * 4096;
#pragma unroll
    for (int k = 0; k < 16; ++k) atomicAdd(yrep + k * 256 + t, num_s[k * 256 + t]);
    if (t < 8) atomicAdd(ws + DREP_OFF + (rep * 8 + b) * 8 + t, den_s[t]);
}

__global__ __launch_bounds__(512) void kV(const float* __restrict__ wv, float* ws) {
    __shared__ float yn_s[512];
    __shared__ float dinv[8];
    int b = blockIdx.x >> 3, cc = blockIdx.x & 7;
    int c0 = cc * 64;
    int t = threadIdx.x;
    if (t < 8) {
        float s = 0.f;
#pragma unroll
        for (int rep = 0; rep < 8; ++rep) s += ws[DREP_OFF + (rep * 8 + b) * 8 + t];
        dinv[t] = 1.f / s;
    }
    __syncthreads();
    {
        int h = t >> 6, cl = t & 63;
        float s = 0.f;
#pragma unroll
        for (int rep = 0; rep < 8; ++rep)
            s += ws[YREP_OFF + ((size_t)rep * 8 + b) * 4096 + h * 512 + c0 + cl];
        yn_s[t] = s * dinv[h];
    }
    __syncthreads();
    int o = t, h = o >> 6;
    const float* yh = yn_s + h * 64;
    float acc = 0.f;
#pragma unroll 8
    for (int ci = 0; ci < 64; ++ci) acc += yh[ci] * wv[(size_t)(c0 + ci) * 512 + o];
    atomicAdd(ws + V_OFF + b * 512 + o, acc);
}

__global__ __launch_bounds__(512) void kRow(const float* __restrict__ wo, float* ws) {
    __shared__ float V_s[64];
    int b = blockIdx.x >> 3, oc = blockIdx.x & 7;
    int o0 = oc * 64;
    int t = threadIdx.x;
    if (t < 64) V_s[t] = ws[V_OFF + b * 512 + o0 + t];
    __syncthreads();
    float acc = 0.f;
#pragma unroll 8
    for (int oi = 0; oi < 64; ++oi) acc += V_s[oi] * wo[(size_t)(o0 + oi) * 512 + t];
    atomicAdd(ws + ROW_OFF + b * 512 + t, acc);
}

__global__ __launch_bounds__(256) void k9_out(const float* __restrict__ ws, float* __restrict__ out) {
    const float4* row4 = (const float4*)(ws + ROW_OFF);
    float4* out4 = (float4*)out;
    size_t stride = (size_t)gridDim.x * blockDim.x;
    for (size_t g = (size_t)blockIdx.x * blockDim.x + threadIdx.x; g < 8388608ull; g += stride) {
        int b = (int)(g >> 20);
        int q = (int)(g & 127);
        out4[g] = row4[b * 128 + q];
    }
}

extern "C" void kernel_launch(void* const* d_in, const int* in_sizes, int n_in,
                              void* d_out, int out_size, void* d_ws, size_t ws_size,
                              hipStream_t stream) {
    const float* x   = (const float*)d_in[0];
    const float* poi = (const float*)d_in[1];
    const float* wq1 = (const float*)d_in[2];
    const float* bq1 = (const float*)d_in[3];
    const float* wq2 = (const float*)d_in[4];
    const float* bq2 = (const float*)d_in[5];
    const float* wk  = (const float*)d_in[6];
    const float* bk  = (const float*)d_in[7];
    const float* wv  = (const float*)d_in[8];
    const float* bv  = (const float*)d_in[9];
    const float* wo  = (const float*)d_in[10];
    const float* bo  = (const float*)d_in[11];
    float* ws  = (float*)d_ws;
    float* out = (float*)d_out;

    void* args[] = { (void*)&x, (void*)&poi, (void*)&wq1, (void*)&bq1, (void*)&wq2,
                     (void*)&bq2, (void*)&wk, (void*)&bk, (void*)&wv, (void*)&bv,
                     (void*)&wo, (void*)&bo, (void*)&ws, (void*)&out };
    hipError_t err = hipLaunchCooperativeKernel((const void*)mega, dim3(512), dim3(256),
                                                args, 0, stream);
    if (err != hipSuccess) {
        // proven round-3 path
        k0_init<<<1060, 256, 0, stream>>>(ws, bv, bo, bq2);
        k1_qraw<<<7, 256, 0, stream>>>(poi, wq1, bq1, ws);
        k2_qf<<<53, 512, 0, stream>>>(wq2, ws);
        k3_qkvec<<<16, 256, 0, stream>>>(wk, bk, ws);
        kF<<<512, 256, 0, stream>>>(x, ws);
        kV<<<64, 512, 0, stream>>>(wv, ws);
        kRow<<<64, 512, 0, stream>>>(wo, ws);
        k9_out<<<2048, 256, 0, stream>>>(ws, out);
    }
}

// Round 6
// 103.294 us; speedup vs baseline: 3.7909x; 3.7909x over previous
//
#include <hip/hip_runtime.h>
#include <math.h>

#define L_SEQ 8192
#define B_N   8

typedef float f4v __attribute__((ext_vector_type(4)));

// Workspace layout (float offsets). ws is large (~512MB); we use ~8.6MB.
#define QRAW_OFF   0                        // [1683]
#define QF_OFF     2048                     // [512]
#define QKV_OFF    2560                     // [8][512] = 4096 (pre-scaled by 0.125)
#define CK_OFF     6656                     // [8] (pre-scaled by 0.125)
#define V_OFF      6720                     // [8][512] = 4096
#define ROW_OFF    10816                    // [8][512] = 4096
#define DPART_OFF  15360                    // [512 slots][8] = 4096
#define YPART_OFF  32768                    // [512 slots][4096] = 2097152 (16B-aligned)

// ---- k01: fused init (V=bv, row=bo, qf=bq2) + qraw ----
__global__ void k01_init(float* ws, const float* __restrict__ poi,
                         const float* __restrict__ wq1, const float* __restrict__ bq1,
                         const float* __restrict__ bv, const float* __restrict__ bo,
                         const float* __restrict__ bq2) {
    int gid = blockIdx.x * 256 + threadIdx.x;
    if (gid < 1683) {
        float a = bq1[0];
#pragma unroll
        for (int j = 0; j < 24; ++j) a += poi[gid * 24 + j] * wq1[j];
        ws[QRAW_OFF + gid] = a;
    } else if (gid >= 2048 && gid < 6144) {
        int i = gid - 2048;
        ws[V_OFF + i] = bv[i & 511];
    } else if (gid >= 6144 && gid < 10240) {
        int i = gid - 6144;
        ws[ROW_OFF + i] = bo[i & 511];
    } else if (gid >= 10240 && gid < 10752) {
        ws[QF_OFF + (gid - 10240)] = bq2[gid - 10240];
    }
}

// ---- k2: qf[o] += sum_{i in chunk} qraw[i]*wq2[i,o]  (qf init'd to bq2) ----
__global__ __launch_bounds__(512) void k2_qf(const float* __restrict__ wq2, float* ws) {
    __shared__ float qr[32];
    int k = blockIdx.x, t = threadIdx.x;
    int i0 = k * 32;
    int cnt = 1683 - i0; if (cnt > 32) cnt = 32;
    if (t < cnt) qr[t] = ws[QRAW_OFF + i0 + t];
    __syncthreads();
    float a = 0.f;
    for (int ii = 0; ii < cnt; ++ii) a += qr[ii] * wq2[(size_t)(i0 + ii) * 512 + t];
    atomicAdd(ws + QF_OFF + t, a);
}

// ---- k3: qkvec[h,c] = 0.125*sum_e qf[h*64+e]*wk[c,h*64+e]; ck[h] = 0.125*qf_h·bk_h ----
__global__ void k3_qkvec(const float* __restrict__ wk, const float* __restrict__ bk, float* ws) {
    __shared__ float qf[512];
    int t = threadIdx.x;
    for (int t2 = t; t2 < 512; t2 += 256) qf[t2] = ws[QF_OFF + t2];
    __syncthreads();
    int idx = blockIdx.x * 256 + t;
    int h = idx >> 9, c = idx & 511;
    float a = 0.f;
#pragma unroll 8
    for (int e = 0; e < 64; ++e) a += qf[h * 64 + e] * wk[(size_t)c * 512 + h * 64 + e];
    ws[QKV_OFF + idx] = 0.125f * a;
    if (idx < 8) {
        float bsum = 0.f;
        for (int e = 0; e < 64; ++e) bsum += qf[idx * 64 + e] * bk[idx * 64 + e];
        ws[CK_OFF + idx] = 0.125f * bsum;
    }
}

// ---- kF: fused pass (scores -> exp -> weighted sum); per-block partial slots, no atomics ----
__global__ __launch_bounds__(256, 2) void kF(const float* __restrict__ x, float* __restrict__ ws) {
    int t = threadIdx.x;
    int lane = t & 63, w = t >> 6;
    int b = blockIdx.x >> 6, slot = blockIdx.x & 63;
    int wslot = slot * 4 + w;                 // 0..255 waves per batch

    float4 qa[8], qb[8];
    const float4* qk4 = (const float4*)(ws + QKV_OFF);
#pragma unroll
    for (int h = 0; h < 8; ++h) {
        qa[h] = qk4[h * 128 + lane * 2];
        qb[h] = qk4[h * 128 + lane * 2 + 1];
    }
    float ck[8];
#pragma unroll
    for (int h = 0; h < 8; ++h) ck[h] = ws[CK_OFF + h];

    float num[8][8] = {{0.f}};
    float den[8] = {0.f};

    const float4* xp = (const float4*)(x + (size_t)b * L_SEQ * 512);
    float4 cxa = xp[(size_t)wslot * 128 + lane * 2];
    float4 cxb = xp[(size_t)wslot * 128 + lane * 2 + 1];

    for (int r = wslot; r < L_SEQ; r += 256) {
        int rn = r + 256;
        float4 nxa = cxa, nxb = cxb;
        if (rn < L_SEQ) {
            nxa = xp[(size_t)rn * 128 + lane * 2];
            nxb = xp[(size_t)rn * 128 + lane * 2 + 1];
        }
        float p[8];
#pragma unroll
        for (int h = 0; h < 8; ++h)
            p[h] = cxa.x * qa[h].x + cxa.y * qa[h].y + cxa.z * qa[h].z + cxa.w * qa[h].w
                 + cxb.x * qb[h].x + cxb.y * qb[h].y + cxb.z * qb[h].z + cxb.w * qb[h].w;
#pragma unroll
        for (int m = 32; m >= 1; m >>= 1) {
#pragma unroll
            for (int h = 0; h < 8; ++h) p[h] += __shfl_xor(p[h], m, 64);
        }
#pragma unroll
        for (int h = 0; h < 8; ++h) {
            float wg = __expf(p[h] + ck[h]);  // logits pre-scaled by 0.125, |logit| small
            den[h] += wg;
            num[h][0] += wg * cxa.x; num[h][1] += wg * cxa.y;
            num[h][2] += wg * cxa.z; num[h][3] += wg * cxa.w;
            num[h][4] += wg * cxb.x; num[h][5] += wg * cxb.y;
            num[h][6] += wg * cxb.z; num[h][7] += wg * cxb.w;
        }
        cxa = nxa; cxb = nxb;
    }

    // staged deterministic block reduction in LDS
    __shared__ float num_s[4096];
    __shared__ float den_s[8];
    for (int wi = 0; wi < 4; ++wi) {
        if (w == wi) {
#pragma unroll
            for (int h = 0; h < 8; ++h) {
                int base = h * 512 + lane * 8;
                if (wi == 0) {
#pragma unroll
                    for (int j = 0; j < 8; ++j) num_s[base + j] = num[h][j];
                    if (lane == 0) den_s[h] = den[h];
                } else {
#pragma unroll
                    for (int j = 0; j < 8; ++j) num_s[base + j] += num[h][j];
                    if (lane == 0) den_s[h] += den[h];
                }
            }
        }
        __syncthreads();
    }
    // plain coalesced partial-slot store (replaces 2M global atomics)
    float4* yp4 = (float4*)(ws + YPART_OFF + (size_t)blockIdx.x * 4096);
    const float4* ns4 = (const float4*)num_s;
#pragma unroll
    for (int k = 0; k < 4; ++k) yp4[k * 256 + t] = ns4[k * 256 + t];
    if (t < 8) ws[DPART_OFF + blockIdx.x * 8 + t] = den_s[t];
}

// ---- kV: reduce 64 partial slots, normalize, V[b,o] += chunk GEMV (V init'd to bv) ----
__global__ __launch_bounds__(512) void kV(const float* __restrict__ wv, float* ws) {
    __shared__ float red[512];
    __shared__ float yn_s[512];   // [h][64c] for this chunk
    __shared__ float dinv[8];
    int b = blockIdx.x >> 3, cc = blockIdx.x & 7;
    int c0 = cc * 64;
    int t = threadIdx.x;
    // den: sum 64 slots x 8 heads
    red[t] = ws[DPART_OFF + (size_t)(b * 64 + (t >> 3)) * 8 + (t & 7)];
    __syncthreads();
#pragma unroll
    for (int off = 256; off >= 8; off >>= 1) {
        if (t < off) red[t] += red[t + off];
        __syncthreads();
    }
    if (t < 8) dinv[t] = 1.f / red[t];
    // y: sum 64 slots for this (h, c) pair
    int h = t >> 6, cl = t & 63;
    float s = 0.f;
    const float* yp = ws + YPART_OFF + (size_t)(b * 64) * 4096 + h * 512 + c0 + cl;
#pragma unroll 8
    for (int sl = 0; sl < 64; ++sl) s += yp[(size_t)sl * 4096];
    __syncthreads();
    yn_s[t] = s * dinv[h];
    __syncthreads();
    int o = t, ho = o >> 6;
    const float* yh = yn_s + ho * 64;
    float acc = 0.f;
#pragma unroll 8
    for (int ci = 0; ci < 64; ++ci) acc += yh[ci] * wv[(size_t)(c0 + ci) * 512 + o];
    atomicAdd(ws + V_OFF + b * 512 + o, acc);
}

// ---- kRow: row[b,j] += sum_{o in chunk} V[b,o]*wo[o,j]  (row init'd to bo) ----
__global__ __launch_bounds__(512) void kRow(const float* __restrict__ wo, float* ws) {
    __shared__ float V_s[64];
    int b = blockIdx.x >> 3, oc = blockIdx.x & 7;
    int o0 = oc * 64;
    int t = threadIdx.x;
    if (t < 64) V_s[t] = ws[V_OFF + b * 512 + o0 + t];
    __syncthreads();
    float acc = 0.f;
#pragma unroll 8
    for (int oi = 0; oi < 64; ++oi) acc += V_s[oi] * wo[(size_t)(o0 + oi) * 512 + t];
    atomicAdd(ws + ROW_OFF + b * 512 + t, acc);
}

// ---- k9: broadcast out[b,l,:] = row[b,:]  (nontemporal stores via ext_vector_type) ----
__global__ __launch_bounds__(256) void k9_out(const float* __restrict__ ws, float* __restrict__ out) {
    const f4v* row4 = (const f4v*)(ws + ROW_OFF);
    f4v* out4 = (f4v*)out;
    size_t stride = (size_t)gridDim.x * blockDim.x;
    for (size_t g = (size_t)blockIdx.x * blockDim.x + threadIdx.x; g < 8388608ull; g += stride) {
        int b = (int)(g >> 20);          // 8192 rows * 128 float4/row = 2^20 per batch
        int q = (int)(g & 127);
        f4v v = row4[b * 128 + q];
        __builtin_nontemporal_store(v, &out4[g]);
    }
}

extern "C" void kernel_launch(void* const* d_in, const int* in_sizes, int n_in,
                              void* d_out, int out_size, void* d_ws, size_t ws_size,
                              hipStream_t stream) {
    const float* x   = (const float*)d_in[0];
    const float* poi = (const float*)d_in[1];
    const float* wq1 = (const float*)d_in[2];
    const float* bq1 = (const float*)d_in[3];
    const float* wq2 = (const float*)d_in[4];
    const float* bq2 = (const float*)d_in[5];
    const float* wk  = (const float*)d_in[6];
    const float* bk  = (const float*)d_in[7];
    const float* wv  = (const float*)d_in[8];
    const float* bv  = (const float*)d_in[9];
    const float* wo  = (const float*)d_in[10];
    const float* bo  = (const float*)d_in[11];
    float* ws  = (float*)d_ws;
    float* out = (float*)d_out;

    k01_init<<<42, 256, 0, stream>>>(ws, poi, wq1, bq1, bv, bo, bq2);
    k2_qf<<<53, 512, 0, stream>>>(wq2, ws);
    k3_qkvec<<<16, 256, 0, stream>>>(wk, bk, ws);
    kF<<<512, 256, 0, stream>>>(x, ws);
    kV<<<64, 512, 0, stream>>>(wv, ws);
    kRow<<<64, 512, 0, stream>>>(wo, ws);
    k9_out<<<2048, 256, 0, stream>>>(ws, out);
}